// Round 7
// baseline (1200.601 us; speedup 1.0000x reference)
//
#include <hip/hip_runtime.h>
#include <hip/hip_bf16.h>

typedef __attribute__((ext_vector_type(4))) float  f32x4;
typedef __attribute__((ext_vector_type(8))) short  bf16x8;
typedef __attribute__((ext_vector_type(4))) float  float4v;
typedef __attribute__((ext_vector_type(8))) unsigned short ushort8;

#define CIO 128
#define BR  120          // out rows per bucket/block
#define BRP 121          // accum lrow stride (odd -> conflict-light ds_add)
#define NB_MAX 896

__device__ __forceinline__ unsigned short f2bf(float f) {
  unsigned int u = __float_as_uint(f);
  u = u + 0x7fffu + ((u >> 16) & 1u);
  return (unsigned short)(u >> 16);
}
__device__ __forceinline__ float bf2f(unsigned short u) {
  return __uint_as_float(((unsigned int)u) << 16);
}

// ============ prep: Wswz[k][kb][nf][lane][8] = B-fragment order ============
__global__ void prep_wswz(const float* __restrict__ W,
                          unsigned short* __restrict__ Wswz, int total) {
  int i = blockIdx.x * 256 + threadIdx.x;
  if (i >= total) return;
  int lane = i & 63;
  int nf   = (i >> 6) & 7;
  int kb   = (i >> 9) & 3;
  int k    = i >> 11;
  int n    = nf * 16 + (lane & 15);
  int c0   = kb * 32 + (lane >> 4) * 8;
  ushort8 v;
  #pragma unroll
  for (int e = 0; e < 8; ++e)
    v[e] = f2bf(W[k * 16384 + (c0 + e) * 128 + n]);
  *(ushort8*)(Wswz + (size_t)i * 8) = v;
}

// ============ prep: fbf = bf16(features) ============
__global__ void prep_fbf(const float* __restrict__ f,
                         unsigned short* __restrict__ fbf, int total8) {
  int i = blockIdx.x * 256 + threadIdx.x;
  if (i >= total8) return;
  const float4v* s = (const float4v*)(f + (size_t)i * 8);
  float4v v0 = s[0], v1 = s[1];
  ushort8 o;
  o[0] = f2bf(v0.x); o[1] = f2bf(v0.y); o[2] = f2bf(v0.z); o[3] = f2bf(v0.w);
  o[4] = f2bf(v1.x); o[5] = f2bf(v1.y); o[6] = f2bf(v1.z); o[7] = f2bf(v1.w);
  *(ushort8*)(fbf + (size_t)i * 8) = o;
}

// ============ build 1: per-k LDS histogram over 120-row buckets ============
__global__ __launch_bounds__(1024) void count27(const int* __restrict__ out_map,
                                                int* __restrict__ counts,
                                                int M, int NB) {
  __shared__ int h[NB_MAX];
  int k = blockIdx.x, t = threadIdx.x;
  for (int i = t; i < NB; i += 1024) h[i] = 0;
  __syncthreads();
  for (int m = t; m < M; m += 1024)
    atomicAdd(&h[out_map[k * M + m] / BR], 1);
  __syncthreads();
  for (int i = t; i < NB; i += 1024) counts[k * NB + i] = h[i];
}

// ============ build 2: exclusive scan over NKEY counts (1 block) ============
__global__ __launch_bounds__(1024) void scan_offsets(const int* __restrict__ counts,
                                                     int* __restrict__ offs, int nkey) {
  __shared__ int part[1024];
  int t = threadIdx.x;
  int chunk = (nkey + 1023) / 1024;
  int lo = t * chunk, hi = min(lo + chunk, nkey);
  int s = 0;
  for (int i = lo; i < hi; ++i) s += counts[i];
  part[t] = s;
  __syncthreads();
  for (int d = 1; d < 1024; d <<= 1) {
    int v = (t >= d) ? part[t - d] : 0;
    __syncthreads();
    part[t] += v;
    __syncthreads();
  }
  int run = (t > 0) ? part[t - 1] : 0;
  for (int i = lo; i < hi; ++i) { offs[i] = run; run += counts[i]; }
  if (t == 1023) offs[nkey] = part[1023];
}

// ============ build 3: per-k LDS-positioned scatter ============
__global__ __launch_bounds__(1024) void scatter27(const int* __restrict__ in_map,
                                                  const int* __restrict__ out_map,
                                                  const int* __restrict__ offs,
                                                  unsigned int* __restrict__ sorted,
                                                  int M, int NB) {
  __shared__ int pos[NB_MAX];
  int k = blockIdx.x, t = threadIdx.x;
  for (int i = t; i < NB; i += 1024) pos[i] = offs[k * NB + i];
  __syncthreads();
  for (int m = t; m < M; m += 1024) {
    int o = out_map[k * M + m];
    int p = atomicAdd(&pos[o / BR], 1);
    sorted[p] = ((unsigned int)in_map[k * M + m] << 7) | (unsigned int)(o % BR);
  }
}

// ============ FUSED: one block per bucket; MFMA -> ds_add into LDS accum ============
// NO min-waves launch_bounds: R5's (512,4) forced a 64/64 VGPR/AGPR split -> spill.
__global__ __launch_bounds__(256) void spconv_fused(
    const unsigned short* __restrict__ fbf,
    const unsigned short* __restrict__ Wswz,
    const unsigned int* __restrict__ sorted,
    const int* __restrict__ offs,
    const float* __restrict__ bias,
    float* __restrict__ out,
    int NB, int n_out, int KVOL) {
  __shared__ float accum[CIO * BRP];   // channel-major: accum[c*BRP + lrow], 61.9 KB
  const int b    = blockIdx.x;
  const int tid  = threadIdx.x;
  const int wave = tid >> 6;
  const int lane = tid & 63;
  const int l16  = lane & 15;
  const int lk   = lane >> 4;

  for (int i = tid; i < CIO * BRP; i += 256) accum[i] = 0.f;
  __syncthreads();

  int tc = 0;
  for (int k = 0; k < KVOL; ++k) {
    const int segS = offs[k * NB + b];
    const int segE = offs[k * NB + b + 1];
    const unsigned short* wk = Wswz + (size_t)k * 16384;
    const int nt = (segE - segS + 31) >> 5;
    for (int t = 0; t < nt; ++t) {
      if ((tc++ & 3) != wave) continue;
      const int base = segS + (t << 5);
      const int i0 = base + l16, i1 = base + 16 + l16;
      unsigned int w0 = (i0 < segE) ? sorted[i0] : 0u;
      unsigned int w1 = (i1 < segE) ? sorted[i1] : 0u;
      int in0 = (int)(w0 >> 7), in1 = (int)(w1 >> 7);

      bf16x8 a[2][4];
      #pragma unroll
      for (int kb = 0; kb < 4; ++kb) {
        a[0][kb] = *(const bf16x8*)(fbf + (size_t)in0 * CIO + kb * 32 + lk * 8);
        a[1][kb] = *(const bf16x8*)(fbf + (size_t)in1 * CIO + kb * 32 + lk * 8);
      }

      #pragma unroll
      for (int h = 0; h < 2; ++h) {
        f32x4 acc[2][4] = {};
        #pragma unroll
        for (int kb = 0; kb < 4; ++kb) {
          const unsigned short* wkb = wk + kb * 4096 + h * 2048;
          #pragma unroll
          for (int nf = 0; nf < 4; ++nf) {
            bf16x8 bfr = *(const bf16x8*)(wkb + nf * 512 + lane * 8);
            acc[0][nf] = __builtin_amdgcn_mfma_f32_16x16x32_bf16(a[0][kb], bfr, acc[0][nf], 0, 0, 0);
            acc[1][nf] = __builtin_amdgcn_mfma_f32_16x16x32_bf16(a[1][kb], bfr, acc[1][nf], 0, 0, 0);
          }
        }
        // D layout: row m = rg*16 + lk*4 + r, col c = h*64 + nf*16 + l16
        // scatter direct from regs: accum[c*BRP + lrow] (<=4-way banks)
        #pragma unroll
        for (int rg = 0; rg < 2; ++rg) {
          unsigned int wsrc = rg ? w1 : w0;
          #pragma unroll
          for (int r = 0; r < 4; ++r) {
            int idx = base + rg * 16 + lk * 4 + r;
            if (idx < segE) {
              int lrow = (int)(__shfl(wsrc, lk * 4 + r) & 127u);
              #pragma unroll
              for (int nf = 0; nf < 4; ++nf)
                atomicAdd(&accum[(h * 64 + nf * 16 + l16) * BRP + lrow], acc[rg][nf][r]);
            }
          }
        }
      }
    }
  }
  __syncthreads();

  // store once: out[b*BR + r][c] = accum[c][r] + bias[c]
  for (int i = tid; i < BR * 32; i += 256) {
    int r = i >> 5, q = i & 31;
    int orow = b * BR + r;
    if (orow < n_out) {
      float4v bi = ((const float4v*)bias)[q];
      float4v v;
      v.x = accum[(4 * q + 0) * BRP + r] + bi.x;
      v.y = accum[(4 * q + 1) * BRP + r] + bi.y;
      v.z = accum[(4 * q + 2) * BRP + r] + bi.z;
      v.w = accum[(4 * q + 3) * BRP + r] + bi.w;
      *(float4v*)(out + (size_t)orow * CIO + q * 4) = v;
    }
  }
}

// ===================== legacy fallback (tiny ws) =====================
__global__ void prep_weights(const float* __restrict__ W,
                             unsigned short* __restrict__ Wt, int total) {
  int idx = blockIdx.x * 256 + threadIdx.x;
  if (idx >= total) return;
  int k  = idx >> 14;
  int n  = (idx >> 7) & 127;
  int kk = idx & 127;
  Wt[idx] = f2bf(W[k * 16384 + kk * 128 + n]);
}
__global__ void init_bias(float* __restrict__ out,
                          const float* __restrict__ bias, int total4) {
  int idx = blockIdx.x * 256 + threadIdx.x;
  if (idx >= total4) return;
  float4v b = ((const float4v*)bias)[idx & 31];
  ((float4v*)out)[idx] = b;
}
__global__ __launch_bounds__(256) void spconv_mfma_legacy(
    const float* __restrict__ features, const unsigned short* __restrict__ Wt,
    const int* __restrict__ in_map, const int* __restrict__ out_map,
    float* __restrict__ out, int M) {
  const int ky = blockIdx.y, m0 = blockIdx.x * 64, tid = threadIdx.x;
  __shared__ unsigned short Alds[64 * CIO];
  __shared__ unsigned short Blds[CIO * CIO];
  {
    const ushort8* src = (const ushort8*)(Wt + ky * 16384);
    #pragma unroll
    for (int i = 0; i < 8; ++i) {
      int chunk = tid + i * 256, byte = chunk * 16;
      int row = byte >> 8, off = byte & 255, sw = off ^ ((row & 7) << 4);
      *(ushort8*)((char*)Blds + row * 256 + sw) = src[chunk];
    }
  }
  {
    int r = tid >> 2, q = tid & 3, m = m0 + r;
    unsigned short tmp[32];
    if (m < M) {
      int frow = in_map[ky * M + m];
      const float4v* src = (const float4v*)(features + frow * CIO + q * 32);
      #pragma unroll
      for (int i = 0; i < 8; ++i) {
        float4v v = src[i];
        tmp[i*4+0]=f2bf(v.x); tmp[i*4+1]=f2bf(v.y); tmp[i*4+2]=f2bf(v.z); tmp[i*4+3]=f2bf(v.w);
      }
    } else {
      #pragma unroll
      for (int i = 0; i < 32; ++i) tmp[i] = 0;
    }
    #pragma unroll
    for (int c = 0; c < 4; ++c) {
      int off = q * 64 + c * 16, sw = off ^ ((r & 7) << 4);
      *(ushort8*)((char*)Alds + r * 256 + sw) = *(ushort8*)(tmp + c * 8);
    }
  }
  __syncthreads();
  const int wid = tid >> 6, lane = tid & 63;
  const int wm = wid >> 1, wn = wid & 1, l16 = lane & 15, lk = lane >> 4;
  f32x4 acc[2][4] = {};
  #pragma unroll
  for (int kb = 0; kb < CIO; kb += 32) {
    bf16x8 af[2], bfr[4];
    #pragma unroll
    for (int mf = 0; mf < 2; ++mf) {
      int row = wm * 32 + mf * 16 + l16, off = (kb + lk * 8) * 2;
      int sw = off ^ ((row & 7) << 4);
      af[mf] = *(const bf16x8*)((const char*)Alds + row * 256 + sw);
    }
    #pragma unroll
    for (int nf = 0; nf < 4; ++nf) {
      int n = wn * 64 + nf * 16 + l16, off = (kb + lk * 8) * 2;
      int sw = off ^ ((n & 7) << 4);
      bfr[nf] = *(const bf16x8*)((const char*)Blds + n * 256 + sw);
    }
    #pragma unroll
    for (int mf = 0; mf < 2; ++mf)
      #pragma unroll
      for (int nf = 0; nf < 4; ++nf)
        acc[mf][nf] = __builtin_amdgcn_mfma_f32_16x16x32_bf16(af[mf], bfr[nf], acc[mf][nf], 0, 0, 0);
  }
  #pragma unroll
  for (int mf = 0; mf < 2; ++mf)
    #pragma unroll
    for (int r = 0; r < 4; ++r) {
      int mrow = wm * 32 + mf * 16 + lk * 4 + r, m = m0 + mrow;
      if (m < M) {
        int orow = out_map[ky * M + m];
        float* dst = out + orow * CIO + wn * 64 + l16;
        #pragma unroll
        for (int nf = 0; nf < 4; ++nf) unsafeAtomicAdd(dst + nf * 16, acc[mf][nf][r]);
      }
    }
}

static inline size_t align256(size_t x) { return (x + 255) & ~(size_t)255; }

extern "C" void kernel_launch(void* const* d_in, const int* in_sizes, int n_in,
                              void* d_out, int out_size, void* d_ws, size_t ws_size,
                              hipStream_t stream) {
  const float* features = (const float*)d_in[0];
  const float* W        = (const float*)d_in[1];
  const float* bias     = (const float*)d_in[2];
  const int*   in_map   = (const int*)d_in[3];
  const int*   out_map  = (const int*)d_in[4];
  float*       out      = (float*)d_out;

  const int KVOL  = in_sizes[1] / (CIO * CIO);     // 27
  const int M     = in_sizes[3] / KVOL;            // 50000
  const int n_out = out_size / CIO;                // 100000
  const int N_IN  = in_sizes[0] / CIO;             // 100000
  const int NB    = (n_out + BR - 1) / BR;         // 834
  const int NKEY  = KVOL * NB;
  const size_t KM = (size_t)KVOL * M;

  const size_t s_wswz = (size_t)KVOL * CIO * CIO * 2;
  const size_t o_cnt  = align256(s_wswz);
  const size_t o_offs = align256(o_cnt + (size_t)NKEY * 4);
  const size_t o_sort = align256(o_offs + ((size_t)NKEY + 1) * 4);
  const size_t o_fbf  = align256(o_sort + KM * 4);
  const size_t need   = o_fbf + (size_t)N_IN * CIO * 2;

  if (NB <= NB_MAX && ws_size >= need) {
    unsigned short* Wswz   = (unsigned short*)d_ws;
    int*            cnt    = (int*)((char*)d_ws + o_cnt);
    int*            offs   = (int*)((char*)d_ws + o_offs);
    unsigned int*   sorted = (unsigned int*)((char*)d_ws + o_sort);
    unsigned short* fbf    = (unsigned short*)((char*)d_ws + o_fbf);

    int wtot = KVOL * 4 * 8 * 64;
    prep_wswz<<<(wtot + 255) / 256, 256, 0, stream>>>(W, Wswz, wtot);
    int total8 = N_IN * CIO / 8;
    prep_fbf<<<(total8 + 255) / 256, 256, 0, stream>>>(features, fbf, total8);
    count27<<<KVOL, 1024, 0, stream>>>(out_map, cnt, M, NB);
    scan_offsets<<<1, 1024, 0, stream>>>(cnt, offs, NKEY);
    scatter27<<<KVOL, 1024, 0, stream>>>(in_map, out_map, offs, sorted, M, NB);

    spconv_fused<<<NB, 256, 0, stream>>>(fbf, Wswz, sorted, offs, bias, out,
                                         NB, n_out, KVOL);
  } else {
    unsigned short* Wt = (unsigned short*)d_ws;
    if (ws_size < s_wswz) return;
    int wtot = KVOL * CIO * CIO;
    prep_weights<<<(wtot + 255) / 256, 256, 0, stream>>>(W, Wt, wtot);
    int total4 = out_size / 4;
    init_bias<<<(total4 + 255) / 256, 256, 0, stream>>>(out, bias, total4);
    dim3 grid((M + 63) / 64, KVOL);
    spconv_mfma_legacy<<<grid, 256, 0, stream>>>(features, Wt, in_map, out_map, out, M);
  }
}

// Round 8
// 744.447 us; speedup vs baseline: 1.6127x; 1.6127x over previous
//
#include <hip/hip_runtime.h>
#include <hip/hip_bf16.h>

typedef __attribute__((ext_vector_type(4))) float  f32x4;
typedef __attribute__((ext_vector_type(8))) short  bf16x8;
typedef __attribute__((ext_vector_type(2))) float  float2v;
typedef __attribute__((ext_vector_type(4))) float  float4v;
typedef __attribute__((ext_vector_type(8))) unsigned short ushort8;

#define CIO 128
#define BR  60           // out rows per bucket (block)
#define RPW 15           // rows per wave (BR / 4 waves)
#define MAXT 64          // per-block tile map capacity
#define NB_MAX 2048      // LDS histogram bound in build kernels

__device__ __forceinline__ unsigned short f2bf(float f) {
  unsigned int u = __float_as_uint(f);
  u = u + 0x7fffu + ((u >> 16) & 1u);
  return (unsigned short)(u >> 16);
}
__device__ __forceinline__ float bf2f(unsigned short u) {
  return __uint_as_float(((unsigned int)u) << 16);
}

// ============ prep: Wswz[k][kb][nf][lane][8] = B-fragment order ============
__global__ void prep_wswz(const float* __restrict__ W,
                          unsigned short* __restrict__ Wswz, int total) {
  int i = blockIdx.x * 256 + threadIdx.x;
  if (i >= total) return;
  int lane = i & 63;
  int nf   = (i >> 6) & 7;
  int kb   = (i >> 9) & 3;
  int k    = i >> 11;
  int n    = nf * 16 + (lane & 15);
  int c0   = kb * 32 + (lane >> 4) * 8;
  ushort8 v;
  #pragma unroll
  for (int e = 0; e < 8; ++e)
    v[e] = f2bf(W[k * 16384 + (c0 + e) * 128 + n]);
  *(ushort8*)(Wswz + (size_t)i * 8) = v;
}

// ============ prep: fbf = bf16(features) ============
__global__ void prep_fbf(const float* __restrict__ f,
                         unsigned short* __restrict__ fbf, int total8) {
  int i = blockIdx.x * 256 + threadIdx.x;
  if (i >= total8) return;
  const float4v* s = (const float4v*)(f + (size_t)i * 8);
  float4v v0 = s[0], v1 = s[1];
  ushort8 o;
  o[0] = f2bf(v0.x); o[1] = f2bf(v0.y); o[2] = f2bf(v0.z); o[3] = f2bf(v0.w);
  o[4] = f2bf(v1.x); o[5] = f2bf(v1.y); o[6] = f2bf(v1.z); o[7] = f2bf(v1.w);
  *(ushort8*)(fbf + (size_t)i * 8) = o;
}

// ============ build 1: per-k LDS histogram over BR-row buckets ============
__global__ __launch_bounds__(1024) void count27(const int* __restrict__ out_map,
                                                int* __restrict__ counts,
                                                int M, int NB) {
  __shared__ int h[NB_MAX];
  int k = blockIdx.x, t = threadIdx.x;
  for (int i = t; i < NB; i += 1024) h[i] = 0;
  __syncthreads();
  for (int m = t; m < M; m += 1024)
    atomicAdd(&h[out_map[k * M + m] / BR], 1);
  __syncthreads();
  for (int i = t; i < NB; i += 1024) counts[k * NB + i] = h[i];
}

// ============ build 2: exclusive scan over NKEY counts (1 block) ============
__global__ __launch_bounds__(1024) void scan_offsets(const int* __restrict__ counts,
                                                     int* __restrict__ offs, int nkey) {
  __shared__ int part[1024];
  int t = threadIdx.x;
  int chunk = (nkey + 1023) / 1024;
  int lo = t * chunk, hi = min(lo + chunk, nkey);
  int s = 0;
  for (int i = lo; i < hi; ++i) s += counts[i];
  part[t] = s;
  __syncthreads();
  for (int d = 1; d < 1024; d <<= 1) {
    int v = (t >= d) ? part[t - d] : 0;
    __syncthreads();
    part[t] += v;
    __syncthreads();
  }
  int run = (t > 0) ? part[t - 1] : 0;
  for (int i = lo; i < hi; ++i) { offs[i] = run; run += counts[i]; }
  if (t == 1023) offs[nkey] = part[1023];
}

// ============ build 3: per-k LDS-positioned scatter ============
__global__ __launch_bounds__(1024) void scatter27(const int* __restrict__ in_map,
                                                  const int* __restrict__ out_map,
                                                  const int* __restrict__ offs,
                                                  unsigned int* __restrict__ sorted,
                                                  int M, int NB) {
  __shared__ int pos[NB_MAX];
  int k = blockIdx.x, t = threadIdx.x;
  for (int i = t; i < NB; i += 1024) pos[i] = offs[k * NB + i];
  __syncthreads();
  for (int m = t; m < M; m += 1024) {
    int o = out_map[k * M + m];
    int p = atomicAdd(&pos[o / BR], 1);
    sorted[p] = ((unsigned int)in_map[k * M + m] << 7) | (unsigned int)(o % BR);
  }
}

// ============ FUSED: MFMA -> LDS staging (plain stores) -> register accum ============
// NO fp atomics anywhere (R4/R5/R7 wall: ~173M LDS-atomic lane-ops = ~1100us).
// Wave w exclusively owns out rows [w*RPW, (w+1)*RPW) of its bucket, accumulated
// in registers (compile-time indexed -> no scratch, rule #20).
__global__ __launch_bounds__(256) void spconv_fused(
    const unsigned short* __restrict__ fbf,
    const unsigned short* __restrict__ Wswz,
    const unsigned int* __restrict__ sorted,
    const int* __restrict__ offs,
    const float* __restrict__ bias,
    float* __restrict__ out,
    int NB, int n_out, int KVOL) {
  __shared__ unsigned short stag[4][32 * 128];   // per-wave 32x128 bf16 (swizzled), 32KB
  __shared__ unsigned char  lrow_lds[128];
  __shared__ unsigned char  tile_k[MAXT];
  __shared__ int            tile_base[MAXT];
  __shared__ int            tile_end[MAXT];
  __shared__ int            ntiles_sh;

  const int b    = blockIdx.x;
  const int tid  = threadIdx.x;
  const int wave = tid >> 6;
  const int lane = tid & 63;
  const int l16  = lane & 15;
  const int lk   = lane >> 4;

  // prologue: thread 0 builds the (k, tile) map
  if (tid == 0) {
    int nt = 0;
    for (int k = 0; k < KVOL; ++k) {
      int s = offs[k * NB + b], e = offs[k * NB + b + 1];
      for (int t = s; t < e && nt < MAXT; t += 32) {
        tile_k[nt] = (unsigned char)k; tile_base[nt] = t; tile_end[nt] = e; ++nt;
      }
    }
    ntiles_sh = nt;
  }

  float accr[RPW][2];
  #pragma unroll
  for (int i = 0; i < RPW; ++i) { accr[i][0] = 0.f; accr[i][1] = 0.f; }
  const float2v bi = ((const float2v*)bias)[lane];

  __syncthreads();
  const int ntiles = ntiles_sh;
  const int nbatch = (ntiles + 3) >> 2;

  for (int bt = 0; bt < nbatch; ++bt) {
    const int T = bt * 4 + wave;
    if (T < ntiles) {
      const int k    = tile_k[T];
      const int base = tile_base[T];
      const int e    = tile_end[T];
      const int i0 = base + l16, i1 = base + 16 + l16;
      unsigned int w0 = (i0 < e) ? sorted[i0] : 0u;
      unsigned int w1 = (i1 < e) ? sorted[i1] : 0u;
      if (lk == 0) {
        lrow_lds[wave * 32 + l16]      = (i0 < e) ? (unsigned char)(w0 & 127u) : (unsigned char)255;
        lrow_lds[wave * 32 + 16 + l16] = (i1 < e) ? (unsigned char)(w1 & 127u) : (unsigned char)255;
      }
      const int in0 = (int)(w0 >> 7), in1 = (int)(w1 >> 7);

      bf16x8 a[2][4];
      #pragma unroll
      for (int kb = 0; kb < 4; ++kb) {
        a[0][kb] = *(const bf16x8*)(fbf + (size_t)in0 * CIO + kb * 32 + lk * 8);
        a[1][kb] = *(const bf16x8*)(fbf + (size_t)in1 * CIO + kb * 32 + lk * 8);
      }
      const unsigned short* wk = Wswz + (size_t)k * 16384;
      #pragma unroll
      for (int h = 0; h < 2; ++h) {
        f32x4 acc[2][4] = {};
        #pragma unroll
        for (int kb = 0; kb < 4; ++kb) {
          const unsigned short* wkb = wk + kb * 4096 + h * 2048;
          #pragma unroll
          for (int nf = 0; nf < 4; ++nf) {
            bf16x8 bfr = *(const bf16x8*)(wkb + nf * 512 + lane * 8);
            acc[0][nf] = __builtin_amdgcn_mfma_f32_16x16x32_bf16(a[0][kb], bfr, acc[0][nf], 0, 0, 0);
            acc[1][nf] = __builtin_amdgcn_mfma_f32_16x16x32_bf16(a[1][kb], bfr, acc[1][nf], 0, 0, 0);
          }
        }
        // D: row m = rg*16 + lk*4 + r, col c = h*64 + nf*16 + l16
        // staging layout (verified R6-A): stag[m*128 + (c ^ (((m>>2)&3)<<4))]
        #pragma unroll
        for (int rg = 0; rg < 2; ++rg)
          #pragma unroll
          for (int r = 0; r < 4; ++r) {
            const int m = rg * 16 + lk * 4 + r;
            #pragma unroll
            for (int nf = 0; nf < 4; ++nf) {
              const int c = h * 64 + nf * 16 + l16;
              stag[wave][m * 128 + (c ^ (lk << 4))] = f2bf(acc[rg][nf][r]);
            }
          }
      }
    } else if (lk == 0) {
      lrow_lds[wave * 32 + l16]      = 255;
      lrow_lds[wave * 32 + 16 + l16] = 255;
    }
    __syncthreads();

    // scatter: each wave register-accumulates batch entries belonging to its rows
    {
      const unsigned int lpack = *(const unsigned short*)&lrow_lds[2 * lane];
      #pragma unroll 1
      for (int e = 0; e < 128; ++e) {
        int lr = (__builtin_amdgcn_readlane(lpack, e >> 1) >> ((e & 1) * 8)) & 255;
        const unsigned int rel = (unsigned int)(lr - wave * RPW);
        if (rel < RPW) {
          const int wp = e >> 5, m = e & 31;
          const int ad = m * 128 + ((2 * lane) ^ (((m >> 2) & 3) << 4));
          const unsigned int u = *(const unsigned int*)&stag[wp][ad];
          const float v0 = bf2f((unsigned short)(u & 0xFFFFu));
          const float v1 = bf2f((unsigned short)(u >> 16));
          #pragma unroll
          for (int rr = 0; rr < RPW; ++rr)
            if (rr == (int)rel) { accr[rr][0] += v0; accr[rr][1] += v1; }
        }
      }
    }
    __syncthreads();
  }

  // epilogue: registers + bias -> out (coalesced, one write per row)
  #pragma unroll
  for (int rr = 0; rr < RPW; ++rr) {
    const int orow = b * BR + wave * RPW + rr;
    if (orow < n_out) {
      float2v o;
      o.x = accr[rr][0] + bi.x;
      o.y = accr[rr][1] + bi.y;
      *(float2v*)(out + (size_t)orow * CIO + 2 * lane) = o;
    }
  }
}

// ===================== legacy fallback (tiny ws) =====================
__global__ void prep_weights(const float* __restrict__ W,
                             unsigned short* __restrict__ Wt, int total) {
  int idx = blockIdx.x * 256 + threadIdx.x;
  if (idx >= total) return;
  int k  = idx >> 14;
  int n  = (idx >> 7) & 127;
  int kk = idx & 127;
  Wt[idx] = f2bf(W[k * 16384 + kk * 128 + n]);
}
__global__ void init_bias(float* __restrict__ out,
                          const float* __restrict__ bias, int total4) {
  int idx = blockIdx.x * 256 + threadIdx.x;
  if (idx >= total4) return;
  float4v b = ((const float4v*)bias)[idx & 31];
  ((float4v*)out)[idx] = b;
}
__global__ __launch_bounds__(256) void spconv_mfma_legacy(
    const float* __restrict__ features, const unsigned short* __restrict__ Wt,
    const int* __restrict__ in_map, const int* __restrict__ out_map,
    float* __restrict__ out, int M) {
  const int ky = blockIdx.y, m0 = blockIdx.x * 64, tid = threadIdx.x;
  __shared__ unsigned short Alds[64 * CIO];
  __shared__ unsigned short Blds[CIO * CIO];
  {
    const ushort8* src = (const ushort8*)(Wt + ky * 16384);
    #pragma unroll
    for (int i = 0; i < 8; ++i) {
      int chunk = tid + i * 256, byte = chunk * 16;
      int row = byte >> 8, off = byte & 255, sw = off ^ ((row & 7) << 4);
      *(ushort8*)((char*)Blds + row * 256 + sw) = src[chunk];
    }
  }
  {
    int r = tid >> 2, q = tid & 3, m = m0 + r;
    unsigned short tmp[32];
    if (m < M) {
      int frow = in_map[ky * M + m];
      const float4v* src = (const float4v*)(features + frow * CIO + q * 32);
      #pragma unroll
      for (int i = 0; i < 8; ++i) {
        float4v v = src[i];
        tmp[i*4+0]=f2bf(v.x); tmp[i*4+1]=f2bf(v.y); tmp[i*4+2]=f2bf(v.z); tmp[i*4+3]=f2bf(v.w);
      }
    } else {
      #pragma unroll
      for (int i = 0; i < 32; ++i) tmp[i] = 0;
    }
    #pragma unroll
    for (int c = 0; c < 4; ++c) {
      int off = q * 64 + c * 16, sw = off ^ ((r & 7) << 4);
      *(ushort8*)((char*)Alds + r * 256 + sw) = *(ushort8*)(tmp + c * 8);
    }
  }
  __syncthreads();
  const int wid = tid >> 6, lane = tid & 63;
  const int wm = wid >> 1, wn = wid & 1, l16 = lane & 15, lk = lane >> 4;
  f32x4 acc[2][4] = {};
  #pragma unroll
  for (int kb = 0; kb < CIO; kb += 32) {
    bf16x8 af[2], bfr[4];
    #pragma unroll
    for (int mf = 0; mf < 2; ++mf) {
      int row = wm * 32 + mf * 16 + l16, off = (kb + lk * 8) * 2;
      int sw = off ^ ((row & 7) << 4);
      af[mf] = *(const bf16x8*)((const char*)Alds + row * 256 + sw);
    }
    #pragma unroll
    for (int nf = 0; nf < 4; ++nf) {
      int n = wn * 64 + nf * 16 + l16, off = (kb + lk * 8) * 2;
      int sw = off ^ ((n & 7) << 4);
      bfr[nf] = *(const bf16x8*)((const char*)Blds + n * 256 + sw);
    }
    #pragma unroll
    for (int mf = 0; mf < 2; ++mf)
      #pragma unroll
      for (int nf = 0; nf < 4; ++nf)
        acc[mf][nf] = __builtin_amdgcn_mfma_f32_16x16x32_bf16(af[mf], bfr[nf], acc[mf][nf], 0, 0, 0);
  }
  #pragma unroll
  for (int mf = 0; mf < 2; ++mf)
    #pragma unroll
    for (int r = 0; r < 4; ++r) {
      int mrow = wm * 32 + mf * 16 + lk * 4 + r, m = m0 + mrow;
      if (m < M) {
        int orow = out_map[ky * M + m];
        float* dst = out + orow * CIO + wn * 64 + l16;
        #pragma unroll
        for (int nf = 0; nf < 4; ++nf) unsafeAtomicAdd(dst + nf * 16, acc[mf][nf][r]);
      }
    }
}

static inline size_t align256(size_t x) { return (x + 255) & ~(size_t)255; }

extern "C" void kernel_launch(void* const* d_in, const int* in_sizes, int n_in,
                              void* d_out, int out_size, void* d_ws, size_t ws_size,
                              hipStream_t stream) {
  const float* features = (const float*)d_in[0];
  const float* W        = (const float*)d_in[1];
  const float* bias     = (const float*)d_in[2];
  const int*   in_map   = (const int*)d_in[3];
  const int*   out_map  = (const int*)d_in[4];
  float*       out      = (float*)d_out;

  const int KVOL  = in_sizes[1] / (CIO * CIO);     // 27
  const int M     = in_sizes[3] / KVOL;            // 50000
  const int n_out = out_size / CIO;                // 100000
  const int N_IN  = in_sizes[0] / CIO;             // 100000
  const int NB    = (n_out + BR - 1) / BR;         // 1667
  const int NKEY  = KVOL * NB;
  const size_t KM = (size_t)KVOL * M;

  const size_t s_wswz = (size_t)KVOL * CIO * CIO * 2;
  const size_t o_cnt  = align256(s_wswz);
  const size_t o_offs = align256(o_cnt + (size_t)NKEY * 4);
  const size_t o_sort = align256(o_offs + ((size_t)NKEY + 1) * 4);
  const size_t o_fbf  = align256(o_sort + KM * 4);
  const size_t need   = o_fbf + (size_t)N_IN * CIO * 2;

  if (NB <= NB_MAX && KVOL <= 32 && ws_size >= need) {
    unsigned short* Wswz   = (unsigned short*)d_ws;
    int*            cnt    = (int*)((char*)d_ws + o_cnt);
    int*            offs   = (int*)((char*)d_ws + o_offs);
    unsigned int*   sorted = (unsigned int*)((char*)d_ws + o_sort);
    unsigned short* fbf    = (unsigned short*)((char*)d_ws + o_fbf);

    int wtot = KVOL * 4 * 8 * 64;
    prep_wswz<<<(wtot + 255) / 256, 256, 0, stream>>>(W, Wswz, wtot);
    int total8 = N_IN * CIO / 8;
    prep_fbf<<<(total8 + 255) / 256, 256, 0, stream>>>(features, fbf, total8);
    count27<<<KVOL, 1024, 0, stream>>>(out_map, cnt, M, NB);
    scan_offsets<<<1, 1024, 0, stream>>>(cnt, offs, NKEY);
    scatter27<<<KVOL, 1024, 0, stream>>>(in_map, out_map, offs, sorted, M, NB);

    spconv_fused<<<NB, 256, 0, stream>>>(fbf, Wswz, sorted, offs, bias, out,
                                         NB, n_out, KVOL);
  } else {
    unsigned short* Wt = (unsigned short*)d_ws;
    if (ws_size < s_wswz) return;
    int wtot = KVOL * CIO * CIO;
    prep_weights<<<(wtot + 255) / 256, 256, 0, stream>>>(W, Wt, wtot);
    int total4 = out_size / 4;
    init_bias<<<(total4 + 255) / 256, 256, 0, stream>>>(out, bias, total4);
    dim3 grid((M + 63) / 64, KVOL);
    spconv_mfma_legacy<<<grid, 256, 0, stream>>>(features, Wt, in_map, out_map, out, M);
  }
}

// Round 9
// 445.726 us; speedup vs baseline: 2.6936x; 1.6702x over previous
//
#include <hip/hip_runtime.h>
#include <hip/hip_bf16.h>

typedef __attribute__((ext_vector_type(4))) float  f32x4;
typedef __attribute__((ext_vector_type(8))) short  bf16x8;
typedef __attribute__((ext_vector_type(2))) float  float2v;
typedef __attribute__((ext_vector_type(4))) float  float4v;
typedef __attribute__((ext_vector_type(8))) unsigned short ushort8;
typedef __attribute__((ext_vector_type(2))) unsigned int uint2v;

#define CIO 128
#define BR  64           // out rows per bucket (= MFMA M of the reduce GEMM)
#define MAXT 96          // per-block tile map capacity (mean ~39)
#define NB_MAX 2048

__device__ __forceinline__ unsigned short f2bf(float f) {
  unsigned int u = __float_as_uint(f);
  u = u + 0x7fffu + ((u >> 16) & 1u);
  return (unsigned short)(u >> 16);
}
__device__ __forceinline__ float bf2f(unsigned short u) {
  return __uint_as_float(((unsigned int)u) << 16);
}

// ============ prep: Wswz[k][kb][nf][lane][8] = B-fragment order ============
__global__ void prep_wswz(const float* __restrict__ W,
                          unsigned short* __restrict__ Wswz, int total) {
  int i = blockIdx.x * 256 + threadIdx.x;
  if (i >= total) return;
  int lane = i & 63;
  int nf   = (i >> 6) & 7;
  int kb   = (i >> 9) & 3;
  int k    = i >> 11;
  int n    = nf * 16 + (lane & 15);
  int c0   = kb * 32 + (lane >> 4) * 8;
  ushort8 v;
  #pragma unroll
  for (int e = 0; e < 8; ++e)
    v[e] = f2bf(W[k * 16384 + (c0 + e) * 128 + n]);
  *(ushort8*)(Wswz + (size_t)i * 8) = v;
}

// ============ prep: fbf = bf16(features) ============
__global__ void prep_fbf(const float* __restrict__ f,
                         unsigned short* __restrict__ fbf, int total8) {
  int i = blockIdx.x * 256 + threadIdx.x;
  if (i >= total8) return;
  const float4v* s = (const float4v*)(f + (size_t)i * 8);
  float4v v0 = s[0], v1 = s[1];
  ushort8 o;
  o[0] = f2bf(v0.x); o[1] = f2bf(v0.y); o[2] = f2bf(v0.z); o[3] = f2bf(v0.w);
  o[4] = f2bf(v1.x); o[5] = f2bf(v1.y); o[6] = f2bf(v1.z); o[7] = f2bf(v1.w);
  *(ushort8*)(fbf + (size_t)i * 8) = o;
}

// ============ build 1: per-k LDS histogram over BR-row buckets ============
__global__ __launch_bounds__(1024) void count27(const int* __restrict__ out_map,
                                                int* __restrict__ counts,
                                                int M, int NB) {
  __shared__ int h[NB_MAX];
  int k = blockIdx.x, t = threadIdx.x;
  for (int i = t; i < NB; i += 1024) h[i] = 0;
  __syncthreads();
  for (int m = t; m < M; m += 1024)
    atomicAdd(&h[out_map[k * M + m] / BR], 1);
  __syncthreads();
  for (int i = t; i < NB; i += 1024) counts[k * NB + i] = h[i];
}

// ============ build 2: exclusive scan over NKEY counts (1 block) ============
__global__ __launch_bounds__(1024) void scan_offsets(const int* __restrict__ counts,
                                                     int* __restrict__ offs, int nkey) {
  __shared__ int part[1024];
  int t = threadIdx.x;
  int chunk = (nkey + 1023) / 1024;
  int lo = t * chunk, hi = min(lo + chunk, nkey);
  int s = 0;
  for (int i = lo; i < hi; ++i) s += counts[i];
  part[t] = s;
  __syncthreads();
  for (int d = 1; d < 1024; d <<= 1) {
    int v = (t >= d) ? part[t - d] : 0;
    __syncthreads();
    part[t] += v;
    __syncthreads();
  }
  int run = (t > 0) ? part[t - 1] : 0;
  for (int i = lo; i < hi; ++i) { offs[i] = run; run += counts[i]; }
  if (t == 1023) offs[nkey] = part[1023];
}

// ============ build 3: per-k LDS-positioned scatter ============
__global__ __launch_bounds__(1024) void scatter27(const int* __restrict__ in_map,
                                                  const int* __restrict__ out_map,
                                                  const int* __restrict__ offs,
                                                  unsigned int* __restrict__ sorted,
                                                  int M, int NB) {
  __shared__ int pos[NB_MAX];
  int k = blockIdx.x, t = threadIdx.x;
  for (int i = t; i < NB; i += 1024) pos[i] = offs[k * NB + i];
  __syncthreads();
  for (int m = t; m < M; m += 1024) {
    int o = out_map[k * M + m];
    int p = atomicAdd(&pos[o / BR], 1);
    sorted[p] = ((unsigned int)in_map[k * M + m] << 7) | (unsigned int)(o % BR);
  }
}

// ============ FUSED: compute-MFMA -> stag_t -> selection-MFMA reduce ============
// The scatter-reduce acc[row][c] += sum_{lrow(e)=row} stag[e][c] is done as
// acc[64x128] += S[64x128] * stag_t[128x128] with S 0/1 bf16 built in registers.
// No atomics, no scans, no runtime-indexed register arrays.
__global__ __launch_bounds__(256) void spconv_fused(
    const unsigned short* __restrict__ fbf,
    const unsigned short* __restrict__ Wswz,
    const unsigned int* __restrict__ sorted,
    const int* __restrict__ offs,
    const float* __restrict__ bias,
    float* __restrict__ out,
    int NB, int n_out, int KVOL) {
  __shared__ __align__(16) unsigned char smem[33792];  // stag_t bf16 128x128 (32KB) / f32 epilogue (33792B)
  __shared__ __align__(8)  unsigned char lrow_lds[128];
  __shared__ unsigned char tile_k[MAXT];
  __shared__ int tile_base[MAXT], tile_end[MAXT];
  __shared__ int seg_s[32], seg_c[32];
  __shared__ int ntiles_sh;

  const int b    = blockIdx.x;
  const int tid  = threadIdx.x;
  const int wave = tid >> 6;
  const int lane = tid & 63;
  const int l16  = lane & 15;
  const int lk   = lane >> 4;
  const int swz  = (l16 & 7) << 4;     // stag_t swizzle (c&7 == l16&7 for all uses)

  // prologue: parallel segment fetch, then tiny serial tile-map build (LDS-only)
  if (tid < KVOL) {
    int s = offs[tid * NB + b], e = offs[tid * NB + b + 1];
    seg_s[tid] = s; seg_c[tid] = e - s;
  }
  __syncthreads();
  if (tid == 0) {
    int nt = 0;
    for (int k = 0; k < KVOL; ++k) {
      int s = seg_s[k], c = seg_c[k];
      for (int t = 0; t < c; t += 32)
        if (nt < MAXT) { tile_k[nt] = (unsigned char)k; tile_base[nt] = s + t; tile_end[nt] = s + c; ++nt; }
    }
    ntiles_sh = nt;
  }
  f32x4 racc[8];
  #pragma unroll
  for (int i = 0; i < 8; ++i) racc[i] = (f32x4){0.f, 0.f, 0.f, 0.f};
  __syncthreads();
  const int ntiles = ntiles_sh;
  const int nbatch = (ntiles + 3) >> 2;

  for (int bt = 0; bt < nbatch; ++bt) {
    const int T = bt * 4 + wave;
    if (T < ntiles) {
      const int k    = tile_k[T];
      const int base = tile_base[T];
      const int e    = tile_end[T];
      const int i0 = base + l16, i1 = base + 16 + l16;
      unsigned int w0 = (i0 < e) ? sorted[i0] : 0u;
      unsigned int w1 = (i1 < e) ? sorted[i1] : 0u;
      if (lk == 0) {
        lrow_lds[wave * 32 + l16]      = (i0 < e) ? (unsigned char)(w0 & 127u) : (unsigned char)255;
        lrow_lds[wave * 32 + 16 + l16] = (i1 < e) ? (unsigned char)(w1 & 127u) : (unsigned char)255;
      }
      const int in0 = (int)(w0 >> 7), in1 = (int)(w1 >> 7);

      bf16x8 a0[4], a1[4];
      #pragma unroll
      for (int kb = 0; kb < 4; ++kb) {
        a0[kb] = *(const bf16x8*)(fbf + (size_t)in0 * CIO + kb * 32 + lk * 8);
        a1[kb] = *(const bf16x8*)(fbf + (size_t)in1 * CIO + kb * 32 + lk * 8);
      }
      const unsigned short* wk = Wswz + (size_t)k * 16384;
      #pragma unroll
      for (int h = 0; h < 2; ++h) {
        f32x4 acc[2][4] = {};
        #pragma unroll
        for (int kb = 0; kb < 4; ++kb) {
          const unsigned short* wkb = wk + kb * 4096 + h * 2048;
          #pragma unroll
          for (int nf = 0; nf < 4; ++nf) {
            bf16x8 bfr = *(const bf16x8*)(wkb + nf * 512 + lane * 8);
            acc[0][nf] = __builtin_amdgcn_mfma_f32_16x16x32_bf16(a0[kb], bfr, acc[0][nf], 0, 0, 0);
            acc[1][nf] = __builtin_amdgcn_mfma_f32_16x16x32_bf16(a1[kb], bfr, acc[1][nf], 0, 0, 0);
          }
        }
        // stag_t[c][e]: D row m = rg*16+lk*4+r (= entry-in-tile), col c = h*64+nf*16+l16.
        // 4 consecutive m per (rg,nf) -> one 8B write; byte ^= swz spreads banks.
        #pragma unroll
        for (int rg = 0; rg < 2; ++rg)
          #pragma unroll
          for (int nf = 0; nf < 4; ++nf) {
            unsigned int lo = f2bf(acc[rg][nf][0]) | ((unsigned int)f2bf(acc[rg][nf][1]) << 16);
            unsigned int hi = f2bf(acc[rg][nf][2]) | ((unsigned int)f2bf(acc[rg][nf][3]) << 16);
            int c  = h * 64 + nf * 16 + l16;
            int eb = (wave * 32 + rg * 16 + lk * 4) * 2;
            *(uint2v*)&smem[c * 256 + (eb ^ swz)] = (uint2v){lo, hi};
          }
      }
    } else if (lk == 0) {
      lrow_lds[wave * 32 + l16]      = 255;
      lrow_lds[wave * 32 + 16 + l16] = 255;
    }
    __syncthreads();

    // reduce: racc[64 rows x 128 ch] += S * stag_t, wave owns rows [wave*16, +16)
    {
      const int target = wave * 16 + l16;
      #pragma unroll
      for (int kb = 0; kb < 4; ++kb) {
        unsigned long long lr8 = *(const unsigned long long*)&lrow_lds[kb * 32 + lk * 8];
        union { unsigned int u[4]; bf16x8 v; } su;
        #pragma unroll
        for (int p = 0; p < 4; ++p) {
          int b0 = (int)((lr8 >> (16 * p)) & 255ull);
          int b1 = (int)((lr8 >> (16 * p + 8)) & 255ull);
          su.u[p] = (b0 == target ? 0x3F80u : 0u) | (b1 == target ? 0x3F800000u : 0u);
        }
        #pragma unroll
        for (int nf = 0; nf < 8; ++nf) {
          int n = nf * 16 + l16;
          bf16x8 bfr = *(const bf16x8*)&smem[n * 256 + (((kb * 32 + lk * 8) * 2) ^ swz)];
          racc[nf] = __builtin_amdgcn_mfma_f32_16x16x32_bf16(su.v, bfr, racc[nf], 0, 0, 0);
        }
      }
    }
    __syncthreads();
  }

  // epilogue: racc -> padded f32 LDS (stride 132: 2-way banks) -> coalesced out
  {
    float* sw32 = (float*)smem + wave * 2112;
    #pragma unroll
    for (int nf = 0; nf < 8; ++nf)
      #pragma unroll
      for (int r = 0; r < 4; ++r)
        sw32[(lk * 4 + r) * 132 + nf * 16 + l16] = racc[nf][r];
    __syncthreads();
    const float2v bi2 = ((const float2v*)bias)[lane];
    #pragma unroll
    for (int rr = 0; rr < 16; ++rr) {
      int orow = b * BR + wave * 16 + rr;
      if (orow < n_out) {
        float2v v = *(float2v*)&sw32[rr * 132 + 2 * lane];
        v.x += bi2.x; v.y += bi2.y;
        *(float2v*)(out + (size_t)orow * CIO + 2 * lane) = v;
      }
    }
  }
}

// ===================== legacy fallback (tiny ws) =====================
__global__ void prep_weights(const float* __restrict__ W,
                             unsigned short* __restrict__ Wt, int total) {
  int idx = blockIdx.x * 256 + threadIdx.x;
  if (idx >= total) return;
  int k  = idx >> 14;
  int n  = (idx >> 7) & 127;
  int kk = idx & 127;
  Wt[idx] = f2bf(W[k * 16384 + kk * 128 + n]);
}
__global__ void init_bias(float* __restrict__ out,
                          const float* __restrict__ bias, int total4) {
  int idx = blockIdx.x * 256 + threadIdx.x;
  if (idx >= total4) return;
  float4v b = ((const float4v*)bias)[idx & 31];
  ((float4v*)out)[idx] = b;
}
__global__ __launch_bounds__(256) void spconv_mfma_legacy(
    const float* __restrict__ features, const unsigned short* __restrict__ Wt,
    const int* __restrict__ in_map, const int* __restrict__ out_map,
    float* __restrict__ out, int M) {
  const int ky = blockIdx.y, m0 = blockIdx.x * 64, tid = threadIdx.x;
  __shared__ unsigned short Alds[64 * CIO];
  __shared__ unsigned short Blds[CIO * CIO];
  {
    const ushort8* src = (const ushort8*)(Wt + ky * 16384);
    #pragma unroll
    for (int i = 0; i < 8; ++i) {
      int chunk = tid + i * 256, byte = chunk * 16;
      int row = byte >> 8, off = byte & 255, sw = off ^ ((row & 7) << 4);
      *(ushort8*)((char*)Blds + row * 256 + sw) = src[chunk];
    }
  }
  {
    int r = tid >> 2, q = tid & 3, m = m0 + r;
    unsigned short tmp[32];
    if (m < M) {
      int frow = in_map[ky * M + m];
      const float4v* src = (const float4v*)(features + frow * CIO + q * 32);
      #pragma unroll
      for (int i = 0; i < 8; ++i) {
        float4v v = src[i];
        tmp[i*4+0]=f2bf(v.x); tmp[i*4+1]=f2bf(v.y); tmp[i*4+2]=f2bf(v.z); tmp[i*4+3]=f2bf(v.w);
      }
    } else {
      #pragma unroll
      for (int i = 0; i < 32; ++i) tmp[i] = 0;
    }
    #pragma unroll
    for (int c = 0; c < 4; ++c) {
      int off = q * 64 + c * 16, sw = off ^ ((r & 7) << 4);
      *(ushort8*)((char*)Alds + r * 256 + sw) = *(ushort8*)(tmp + c * 8);
    }
  }
  __syncthreads();
  const int wid = tid >> 6, lane = tid & 63;
  const int wm = wid >> 1, wn = wid & 1, l16 = lane & 15, lk = lane >> 4;
  f32x4 acc[2][4] = {};
  #pragma unroll
  for (int kb = 0; kb < CIO; kb += 32) {
    bf16x8 af[2], bfr[4];
    #pragma unroll
    for (int mf = 0; mf < 2; ++mf) {
      int row = wm * 32 + mf * 16 + l16, off = (kb + lk * 8) * 2;
      int sw = off ^ ((row & 7) << 4);
      af[mf] = *(const bf16x8*)((const char*)Alds + row * 256 + sw);
    }
    #pragma unroll
    for (int nf = 0; nf < 4; ++nf) {
      int n = wn * 64 + nf * 16 + l16, off = (kb + lk * 8) * 2;
      int sw = off ^ ((n & 7) << 4);
      bfr[nf] = *(const bf16x8*)((const char*)Blds + n * 256 + sw);
    }
    #pragma unroll
    for (int mf = 0; mf < 2; ++mf)
      #pragma unroll
      for (int nf = 0; nf < 4; ++nf)
        acc[mf][nf] = __builtin_amdgcn_mfma_f32_16x16x32_bf16(af[mf], bfr[nf], acc[mf][nf], 0, 0, 0);
  }
  #pragma unroll
  for (int mf = 0; mf < 2; ++mf)
    #pragma unroll
    for (int r = 0; r < 4; ++r) {
      int mrow = wm * 32 + mf * 16 + lk * 4 + r, m = m0 + mrow;
      if (m < M) {
        int orow = out_map[ky * M + m];
        float* dst = out + orow * CIO + wn * 64 + l16;
        #pragma unroll
        for (int nf = 0; nf < 4; ++nf) unsafeAtomicAdd(dst + nf * 16, acc[mf][nf][r]);
      }
    }
}

static inline size_t align256(size_t x) { return (x + 255) & ~(size_t)255; }

extern "C" void kernel_launch(void* const* d_in, const int* in_sizes, int n_in,
                              void* d_out, int out_size, void* d_ws, size_t ws_size,
                              hipStream_t stream) {
  const float* features = (const float*)d_in[0];
  const float* W        = (const float*)d_in[1];
  const float* bias     = (const float*)d_in[2];
  const int*   in_map   = (const int*)d_in[3];
  const int*   out_map  = (const int*)d_in[4];
  float*       out      = (float*)d_out;

  const int KVOL  = in_sizes[1] / (CIO * CIO);     // 27
  const int M     = in_sizes[3] / KVOL;            // 50000
  const int n_out = out_size / CIO;                // 100000
  const int N_IN  = in_sizes[0] / CIO;             // 100000
  const int NB    = (n_out + BR - 1) / BR;         // 1563
  const int NKEY  = KVOL * NB;
  const size_t KM = (size_t)KVOL * M;

  const size_t s_wswz = (size_t)KVOL * CIO * CIO * 2;
  const size_t o_cnt  = align256(s_wswz);
  const size_t o_offs = align256(o_cnt + (size_t)NKEY * 4);
  const size_t o_sort = align256(o_offs + ((size_t)NKEY + 1) * 4);
  const size_t o_fbf  = align256(o_sort + KM * 4);
  const size_t need   = o_fbf + (size_t)N_IN * CIO * 2;

  if (NB <= NB_MAX && KVOL <= 32 && ws_size >= need) {
    unsigned short* Wswz   = (unsigned short*)d_ws;
    int*            cnt    = (int*)((char*)d_ws + o_cnt);
    int*            offs   = (int*)((char*)d_ws + o_offs);
    unsigned int*   sorted = (unsigned int*)((char*)d_ws + o_sort);
    unsigned short* fbf    = (unsigned short*)((char*)d_ws + o_fbf);

    int wtot = KVOL * 4 * 8 * 64;
    prep_wswz<<<(wtot + 255) / 256, 256, 0, stream>>>(W, Wswz, wtot);
    int total8 = N_IN * CIO / 8;
    prep_fbf<<<(total8 + 255) / 256, 256, 0, stream>>>(features, fbf, total8);
    count27<<<KVOL, 1024, 0, stream>>>(out_map, cnt, M, NB);
    scan_offsets<<<1, 1024, 0, stream>>>(cnt, offs, NKEY);
    scatter27<<<KVOL, 1024, 0, stream>>>(in_map, out_map, offs, sorted, M, NB);

    spconv_fused<<<NB, 256, 0, stream>>>(fbf, Wswz, sorted, offs, bias, out,
                                         NB, n_out, KVOL);
  } else {
    unsigned short* Wt = (unsigned short*)d_ws;
    if (ws_size < s_wswz) return;
    int wtot = KVOL * CIO * CIO;
    prep_weights<<<(wtot + 255) / 256, 256, 0, stream>>>(W, Wt, wtot);
    int total4 = out_size / 4;
    init_bias<<<(total4 + 255) / 256, 256, 0, stream>>>(out, bias, total4);
    dim3 grid((M + 63) / 64, KVOL);
    spconv_mfma_legacy<<<grid, 256, 0, stream>>>(features, Wt, in_map, out_map, out, M);
  }
}